// Round 7
// baseline (296.526 us; speedup 1.0000x reference)
//
#include <hip/hip_runtime.h>
#include <cstdint>
#include <cstddef>

// ---------------------------------------------------------------------------
// SelfAttnV2: x[4,2048,1024] fp32 -> QKV proj -> softmax(QK^T/32) V -> out proj
// bf16 MFMA GEMMs, fp32 accum. Reassociated: (P.V).Wo == P.(V.Wo).
//  - QKV / VWT / PVW: gemm97b = 128x128, BK=32, 4 waves.
//    A via 3-slot LDS ring (24 KiB). B DIRECT global->VGPR (L2), double-buffered.
//    Rationale: gemm97 was LDS-BW bound (64KB/iter = 250cy vs 78cy MFMA = 31%
//    ceiling, matches measured 29%). B-direct cuts LDS to 24KB/iter; B rides
//    the L2 port instead -> ~64% ceiling.
//  - SC: 256x256 8-phase template, 256 blocks = 1 clean round (measured-good).
// ---------------------------------------------------------------------------

typedef __bf16 bf16;
typedef __bf16 bf16x8 __attribute__((ext_vector_type(8)));
typedef __bf16 bf16x4 __attribute__((ext_vector_type(4)));
typedef float  f32x4  __attribute__((ext_vector_type(4)));

#define UNIT 8192    // SC staging unit: 128 rows x 64 k = 16 KiB
#define U97  4096    // gemm97b A unit: 128 rows x 32 k = 8 KiB

__device__ __forceinline__ void gload_lds16(const bf16* g, bf16* l) {
  __builtin_amdgcn_global_load_lds(
      (const __attribute__((address_space(1))) unsigned int*)g,
      (__attribute__((address_space(3))) unsigned int*)l, 16, 0, 0);
}

#define GATE(N)  asm volatile("s_waitcnt vmcnt(" #N ")" ::: "memory")
#define LGKM0()  asm volatile("s_waitcnt lgkmcnt(0)" ::: "memory")
#define SBAR()   __builtin_amdgcn_s_barrier()
#define SCHED0() __builtin_amdgcn_sched_barrier(0)

// ===========================================================================
// gemm97b: 128x128, BK=32, 256 threads = 4 waves (2x2), wave tile 64x64.
// A: LDS ring of 3 slots (128x32 each), swizzle slot' = s ^ ((r>>1)&3).
// B: direct global->reg, 4 frags/iter, register double-buffer (unroll-2).
// Per-iter vmem issue: 4 B-loads(t+1) + 2 A-stages(t+2) = 6; GATE(6) pre-MFMA.
// ===========================================================================
__device__ __forceinline__ void stage97(const bf16* g0, long ld, bf16* u, int tid) {
  const int wv = tid >> 6;
  #pragma unroll
  for (int j = 0; j < 2; ++j) {
    const int c = j * 256 + tid;            // 0..511 chunks of 16B
    const int r = c >> 2, s = c & 3;
    const int sg = s ^ ((r >> 1) & 3);
    const int cb = j * 256 + (wv << 6);     // wave-uniform chunk base
    gload_lds16(g0 + (long)r * ld + sg * 8, u + (size_t)cb * 8);
  }
}

__device__ __forceinline__ bf16x8 rd97(const bf16* u, int r, int s) {
  return *(const bf16x8*)(u + (size_t)r * 32 + (size_t)((s ^ ((r >> 1) & 3)) * 8));
}

// one K-iter. PF2: stage A(t+2); PF1: load B(t+1) into bnxt.
template <bool PF2, bool PF1>
__device__ __forceinline__ void iter97(
    int t, int rs, int ns, const bf16* Ag, long lda, const bf16* Bl, long ldb,
    bf16 (*lds)[U97], bf16x8 (&bcur)[4], bf16x8 (&bnxt)[4],
    f32x4 (&acc)[4][4], int tid, int wr, int lr, int lh) {
  bf16x8 aF[4];
  #pragma unroll
  for (int i = 0; i < 4; ++i) aF[i] = rd97(&lds[rs][0], wr * 64 + i * 16 + lr, lh);
  if (PF1) {
    #pragma unroll
    for (int nf = 0; nf < 4; ++nf)
      bnxt[nf] = *(const bf16x8*)(Bl + ((long)(t + 1) << 5) + (long)nf * 16 * ldb);
  }
  if (PF2) stage97(Ag + (long)(t + 2) * 32, lda, &lds[ns][0], tid);
  LGKM0();
  if (PF2) { GATE(6); } else if (PF1) { GATE(4); } else { GATE(0); }
  SCHED0();
  __builtin_amdgcn_s_setprio(1);
  #pragma unroll
  for (int i = 0; i < 4; ++i)
    #pragma unroll
    for (int j = 0; j < 4; ++j)
      acc[i][j] = __builtin_amdgcn_mfma_f32_16x16x32_bf16(aF[i], bcur[j], acc[i][j], 0, 0, 0);
  __builtin_amdgcn_s_setprio(0);
  SBAR();
}

// MODE 0: QKV (+bias -> Q|K|V row-major)  MODE 2: bf16 store  MODE 3: fp32 (+bias)
template <int MODE>
__device__ __forceinline__ void gemm97_body(
    const bf16* __restrict__ A, long sAz, int lda,
    const bf16* __restrict__ B, long sBz, int ldb, int K,
    bf16* __restrict__ p0, long sCz, int ldc,
    bf16* __restrict__ p1, bf16* __restrict__ p2,
    float* __restrict__ fout, long sFz,
    const float* __restrict__ bias, float scale) {
  __shared__ bf16 lds[3][U97];   // 24 KiB (A only)
  const int tid = threadIdx.x;
  const int wv = tid >> 6, ln = tid & 63;
  const int wr = wv >> 1, wc = wv & 1;     // 2x2 waves, 64x64 each
  const int lr = ln & 15, lh = ln >> 4;
  const int m0 = blockIdx.x * 128, n0 = blockIdx.y * 128;
  const int z = blockIdx.z;
  const bf16* Ag = A + (long)z * sAz + (long)m0 * lda;
  const bf16* Bg = B + (long)z * sBz + (long)n0 * ldb;
  // per-lane B base: row n0 + wc*64 + lr, k-offset lh*8
  const bf16* Bl = Bg + (size_t)(wc * 64 + lr) * ldb + lh * 8;
  const int NT = K / 32;

  // prologue: A(0)->slot0, A(1)->slot1 (4 ops), B(0) (4 ops)
  stage97(Ag,      lda, &lds[0][0], tid);
  stage97(Ag + 32, lda, &lds[1][0], tid);
  bf16x8 bX[4], bY[4];
  #pragma unroll
  for (int nf = 0; nf < 4; ++nf)
    bX[nf] = *(const bf16x8*)(Bl + (long)nf * 16 * ldb);
  GATE(6);    // drain A(0); leave {A(1),B(0)}
  SCHED0();
  SBAR();

  f32x4 acc[4][4];
  #pragma unroll
  for (int i = 0; i < 4; ++i)
    #pragma unroll
    for (int j = 0; j < 4; ++j) acc[i][j] = f32x4{0.f, 0.f, 0.f, 0.f};

  int rs = 0, ns = 2;
  int t = 0;
  for (; t + 3 < NT; t += 2) {
    iter97<true, true>(t, rs, ns, Ag, lda, Bl, ldb, lds, bX, bY, acc, tid, wr, lr, lh);
    rs = (rs == 2) ? 0 : rs + 1;  ns = (ns == 2) ? 0 : ns + 1;
    iter97<true, true>(t + 1, rs, ns, Ag, lda, Bl, ldb, lds, bY, bX, acc, tid, wr, lr, lh);
    rs = (rs == 2) ? 0 : rs + 1;  ns = (ns == 2) ? 0 : ns + 1;
  }
  // tail: t = NT-2 (load B(NT-1), no stage), t = NT-1 (nothing)
  iter97<false, true>(t, rs, ns, Ag, lda, Bl, ldb, lds, bX, bY, acc, tid, wr, lr, lh);
  rs = (rs == 2) ? 0 : rs + 1;  ns = (ns == 2) ? 0 : ns + 1;
  iter97<false, false>(t + 1, rs, ns, Ag, lda, Bl, ldb, lds, bY, bX, acc, tid, wr, lr, lh);

  // epilogue: C/D layout col=lane&15, row=(lane>>4)*4+reg
  #pragma unroll
  for (int mf = 0; mf < 4; ++mf) {
    #pragma unroll
    for (int nf = 0; nf < 4; ++nf) {
      #pragma unroll
      for (int rg = 0; rg < 4; ++rg) {
        const int gm = m0 + wr * 64 + mf * 16 + lh * 4 + rg;
        const int gn = n0 + wc * 64 + nf * 16 + lr;
        float v = acc[mf][nf][rg];
        if constexpr (MODE == 0) {
          v += bias[gn];
          if (gn < 1024)       p0[(size_t)gm * 1024 + gn] = (bf16)v;          // Q
          else if (gn < 2048)  p1[(size_t)gm * 1024 + (gn - 1024)] = (bf16)v; // K
          else                 p2[(size_t)gm * 1024 + (gn - 2048)] = (bf16)v; // V
        } else if constexpr (MODE == 2) {
          p0[(size_t)z * sCz + (size_t)gm * ldc + gn] = (bf16)(v * scale);
        } else {
          fout[(size_t)z * sFz + (size_t)gm * ldc + gn] = v + bias[gn];
        }
      }
    }
  }
}

#define GEMM_ARGS const bf16* A, long sAz, int lda, const bf16* B, long sBz, int ldb, \
                  int K, bf16* p0, long sCz, int ldc, bf16* p1, bf16* p2,             \
                  float* fout, long sFz, const float* bias, float scale
__global__ __launch_bounds__(256, 3) void gemm_qkv(GEMM_ARGS) {
  gemm97_body<0>(A, sAz, lda, B, sBz, ldb, K, p0, sCz, ldc, p1, p2, fout, sFz, bias, scale);
}
__global__ __launch_bounds__(256, 3) void gemm_vwt(GEMM_ARGS) {
  gemm97_body<2>(A, sAz, lda, B, sBz, ldb, K, p0, sCz, ldc, p1, p2, fout, sFz, bias, scale);
}
__global__ __launch_bounds__(256, 3) void gemm_pvw(GEMM_ARGS) {
  gemm97_body<3>(A, sAz, lda, B, sBz, ldb, K, p0, sCz, ldc, p1, p2, fout, sFz, bias, scale);
}

// ===========================================================================
// SC: 256x256 8-phase (unchanged, measured-good). 512 threads, 8 waves 2M x 4N.
// ===========================================================================
#define THREADS8 512

__device__ __forceinline__ void stage_unit(const bf16* g0, long ld, bf16* ldsu, int tid) {
  const int wv = tid >> 6;
  #pragma unroll
  for (int j = 0; j < 2; ++j) {
    const int c = j * 512 + tid;
    const int r = c >> 3;
    const int sg = (c & 7) ^ (r & 7);
    const int cb = j * 512 + (wv << 6);
    gload_lds16(g0 + (long)r * ld + sg * 8, ldsu + (size_t)cb * 8);
  }
}

__device__ __forceinline__ bf16x8 rd_frag(const bf16* unitb, int r, int s) {
  return *(const bf16x8*)(unitb + (size_t)r * 64 + (size_t)((s ^ (r & 7)) * 8));
}

#define PHASE(DB, MH, NH, RA, RB, STAGE_CODE, GATE_CODE)                         \
  {                                                                              \
    if (RA) {                                                                    \
      _Pragma("unroll") for (int mf = 0; mf < 4; ++mf)                           \
        _Pragma("unroll") for (int ks = 0; ks < 2; ++ks)                         \
          aF[mf][ks] = rd_frag(&lds[DB][MH][0], wsm * 64 + mf * 16 + lr, ks * 4 + lh); \
    }                                                                            \
    if (RB) {                                                                    \
      _Pragma("unroll") for (int nf = 0; nf < 2; ++nf)                           \
        _Pragma("unroll") for (int ks = 0; ks < 2; ++ks)                         \
          bF[NH][nf][ks] = rd_frag(&lds[DB][2 + NH][0], wsn * 32 + nf * 16 + lr, ks * 4 + lh); \
    }                                                                            \
    STAGE_CODE;                                                                  \
    SBAR();                                                                      \
    LGKM0();                                                                     \
    SCHED0();                                                                    \
    __builtin_amdgcn_s_setprio(1);                                               \
    _Pragma("unroll") for (int mf = 0; mf < 4; ++mf)                             \
      _Pragma("unroll") for (int nf = 0; nf < 2; ++nf)                           \
        _Pragma("unroll") for (int ks = 0; ks < 2; ++ks)                         \
          acc[(MH)*4 + mf][(NH)*2 + nf] = __builtin_amdgcn_mfma_f32_16x16x32_bf16( \
              aF[mf][ks], bF[NH][nf][ks], acc[(MH)*4 + mf][(NH)*2 + nf], 0, 0, 0); \
    __builtin_amdgcn_s_setprio(0);                                               \
    GATE_CODE;                                                                   \
    SBAR();                                                                      \
    SCHED0();                                                                    \
  }

__global__ __launch_bounds__(THREADS8, 2) void gemm_sc(
    const bf16* __restrict__ A, long sAz, int lda,
    const bf16* __restrict__ B, long sBz, int ldb, int K,
    bf16* __restrict__ p0, long sCz, float scale) {
  __shared__ bf16 lds[2][4][UNIT];   // 128 KiB
  const int tid = threadIdx.x;
  const int wv = tid >> 6, ln = tid & 63;
  const int wsm = wv >> 2, wsn = wv & 3;
  const int lr = ln & 15, lh = ln >> 4;

  const int gx = gridDim.x, gy = gridDim.y;
  const int lin = blockIdx.x + gx * (blockIdx.y + gy * blockIdx.z);
  const int nwg = gx * gy * gridDim.z;
  const int swz = (lin & 7) * (nwg >> 3) + (lin >> 3);
  const int by = swz % gy;
  const int t2 = swz / gy;
  const int bx = t2 % gx;
  const int z  = t2 / gx;

  const int m0 = bx * 256, n0 = by * 256;
  const bf16* Ag = A + (long)z * sAz + (long)m0 * lda;
  const bf16* Bg = B + (long)z * sBz + (long)n0 * ldb;
  const int NITER = K / 128;

  stage_unit(Ag,             lda, &lds[0][0][0], tid);
  stage_unit(Bg,             ldb, &lds[0][2][0], tid);
  stage_unit(Ag + 128 * lda, lda, &lds[0][1][0], tid);
  stage_unit(Bg + 128 * ldb, ldb, &lds[0][3][0], tid);
  stage_unit(Ag + 64,        lda, &lds[1][0][0], tid);
  stage_unit(Bg + 64,        ldb, &lds[1][2][0], tid);
  GATE(8);
  SBAR();
  SCHED0();

  f32x4 acc[8][4];
  #pragma unroll
  for (int i = 0; i < 8; ++i)
    #pragma unroll
    for (int j = 0; j < 4; ++j) acc[i][j] = f32x4{0.f, 0.f, 0.f, 0.f};
  bf16x8 aF[4][2], bF[2][2][2];

  for (int it = 0; it < NITER; ++it) {
    const bool nl = (it + 1 < NITER);
    const long ktA = 2L * it + 1, ktB = 2L * it + 2, ktC = 2L * it + 3;
    PHASE(0, 0, 0, 1, 1,
      { stage_unit(Ag + 128 * lda + ktA * 64, lda, &lds[1][1][0], tid); },
      { GATE(6); });
    PHASE(0, 0, 1, 0, 1,
      { stage_unit(Bg + 128 * ldb + ktA * 64, ldb, &lds[1][3][0], tid); },
      { GATE(10); });
    PHASE(0, 1, 0, 1, 0,
      { if (nl) stage_unit(Ag + ktB * 64, lda, &lds[0][0][0], tid); },
      {});
    PHASE(0, 1, 1, 0, 0,
      { if (nl) stage_unit(Bg + ktB * 64, ldb, &lds[0][2][0], tid); },
      { if (nl) { GATE(8); } else { GATE(4); } });
    PHASE(1, 0, 0, 1, 1,
      { if (nl) stage_unit(Ag + 128 * lda + ktB * 64, lda, &lds[0][1][0], tid); },
      { if (nl) { GATE(6); } else { GATE(0); } });
    PHASE(1, 0, 1, 0, 1,
      { if (nl) stage_unit(Bg + 128 * ldb + ktB * 64, ldb, &lds[0][3][0], tid); },
      { GATE(10); });
    PHASE(1, 1, 0, 1, 0,
      { if (nl) stage_unit(Ag + ktC * 64, lda, &lds[1][0][0], tid); },
      {});
    PHASE(1, 1, 1, 0, 0,
      { if (nl) stage_unit(Bg + ktC * 64, ldb, &lds[1][2][0], tid); },
      { GATE(8); });
  }

  #pragma unroll
  for (int mi = 0; mi < 8; ++mi) {
    #pragma unroll
    for (int ni = 0; ni < 4; ++ni) {
      #pragma unroll
      for (int rg = 0; rg < 4; ++rg) {
        const int gm = m0 + (mi >> 2) * 128 + wsm * 64 + (mi & 3) * 16 + lh * 4 + rg;
        const int gn = n0 + (ni >> 1) * 128 + wsn * 32 + (ni & 1) * 16 + lr;
        p0[(size_t)z * sCz + (size_t)gm * 2048 + gn] = (bf16)(acc[mi][ni][rg] * scale);
      }
    }
  }
}

// ===========================================================================
__global__ __launch_bounds__(256) void k_f32_to_bf16(const float* __restrict__ in,
                                                     bf16* __restrict__ out, long n) {
  long i = ((long)blockIdx.x * blockDim.x + threadIdx.x) * 4;
  if (i + 3 < n) {
    float4 v = *(const float4*)(in + i);
    bf16x4 o;
    o[0] = (bf16)v.x; o[1] = (bf16)v.y; o[2] = (bf16)v.z; o[3] = (bf16)v.w;
    *(bf16x4*)(out + i) = o;
  }
}

__global__ __launch_bounds__(256) void k_transpose(const float* __restrict__ in,
                                                   bf16* __restrict__ out, int R, int C) {
  __shared__ float t[32][33];
  int c0 = blockIdx.x * 32, r0 = blockIdx.y * 32;
  int tx = threadIdx.x, ty = threadIdx.y;
  #pragma unroll
  for (int dy = 0; dy < 32; dy += 8)
    t[ty + dy][tx] = in[(size_t)(r0 + ty + dy) * C + c0 + tx];
  __syncthreads();
  #pragma unroll
  for (int dy = 0; dy < 32; dy += 8)
    out[(size_t)(c0 + ty + dy) * R + r0 + tx] = (bf16)t[tx][ty + dy];
}

__global__ __launch_bounds__(256) void k_softmax(bf16* __restrict__ S) {
  const int row = blockIdx.x;
  bf16* p = S + (size_t)row * 2048;
  const int tid = threadIdx.x;
  bf16x8 vin = *(const bf16x8*)(p + tid * 8);
  float x[8];
  float mx = -1e30f;
  #pragma unroll
  for (int i = 0; i < 8; ++i) { x[i] = (float)vin[i]; mx = fmaxf(mx, x[i]); }
  #pragma unroll
  for (int off = 32; off; off >>= 1) mx = fmaxf(mx, __shfl_down(mx, off));
  __shared__ float redm[4];
  if ((tid & 63) == 0) redm[tid >> 6] = mx;
  __syncthreads();
  mx = fmaxf(fmaxf(redm[0], redm[1]), fmaxf(redm[2], redm[3]));
  float s = 0.f;
  #pragma unroll
  for (int i = 0; i < 8; ++i) { x[i] = __expf(x[i] - mx); s += x[i]; }
  #pragma unroll
  for (int off = 32; off; off >>= 1) s += __shfl_down(s, off);
  __shared__ float reds[4];
  if ((tid & 63) == 0) reds[tid >> 6] = s;
  __syncthreads();
  s = reds[0] + reds[1] + reds[2] + reds[3];
  float inv = 1.0f / s;
  bf16x8 vo;
  #pragma unroll
  for (int i = 0; i < 8; ++i) vo[i] = (bf16)(x[i] * inv);
  *(bf16x8*)(p + tid * 8) = vo;
}

// ---------------------------------------------------------------------------
extern "C" void kernel_launch(void* const* d_in, const int* in_sizes, int n_in,
                              void* d_out, int out_size, void* d_ws, size_t ws_size,
                              hipStream_t stream) {
  const float* x    = (const float*)d_in[0];
  const float* Wqkv = (const float*)d_in[1];
  const float* bqkv = (const float*)d_in[2];
  const float* Wout = (const float*)d_in[3];
  const float* bout = (const float*)d_in[4];
  float* out = (float*)d_out;

  char* w = (char*)d_ws;
  const size_t MB = 1ull << 20;
  bf16* Xb  = (bf16*)(w);             // 16MB
  bf16* WqT = (bf16*)(w + 16 * MB);   //  6MB
  bf16* WoT = (bf16*)(w + 22 * MB);   //  2MB
  bf16* Qb  = (bf16*)(w + 24 * MB);   // 16MB
  bf16* Kb  = (bf16*)(w + 40 * MB);   // 16MB
  bf16* Vb  = (bf16*)(w + 56 * MB);   // 16MB
  bf16* Sb  = (bf16*)(w + 72 * MB);   // 32MB (S -> P in place)
  bf16* VWT = (bf16*)(w + 104 * MB);  // 16MB [4][1024][2048]  (total 120MB)

  k_f32_to_bf16<<<8192, 256, 0, stream>>>(x, Xb, 8388608L);
  dim3 tb(32, 8);
  k_transpose<<<dim3(96, 32), tb, 0, stream>>>(Wqkv, WqT, 1024, 3072);
  k_transpose<<<dim3(32, 32), tb, 0, stream>>>(Wout, WoT, 1024, 1024);

  // QKV: [8192,1024] x W^T[3072,1024] + bias -> Q,K,V   (1536 blocks)
  gemm_qkv<<<dim3(64, 24), 256, 0, stream>>>(
      Xb, 0L, 1024, WqT, 0L, 1024, 1024,
      Qb, 0L, 1024, Kb, Vb, nullptr, 0L, bqkv, 1.0f);

  // VWT[z][d][s] = sum_h WoT[d][h] * V[z][s][h]   (512 blocks; V row-major)
  gemm_vwt<<<dim3(8, 16, 4), 256, 0, stream>>>(
      WoT, 0L, 1024, Vb, 2048L * 1024, 1024, 1024,
      VWT, 1024L * 2048, 2048, nullptr, nullptr, nullptr, 0L, nullptr, 1.0f);

  // scores: per batch Q x K^T * 1/32   (8-phase 256^2, 256 blocks = 1 round)
  gemm_sc<<<dim3(8, 8, 4), THREADS8, 0, stream>>>(
      Qb, 2048L * 1024, 1024, Kb, 2048L * 1024, 1024, 1024,
      Sb, 2048L * 2048, 0.03125f);

  k_softmax<<<8192, 256, 0, stream>>>(Sb);

  // out[z][q][d] = sum_s P[z][q][s] * VWT[z][d][s] + bout[d]   (512 blocks, fp32)
  gemm_pvw<<<dim3(16, 8, 4), 256, 0, stream>>>(
      Sb, 2048L * 2048, 2048, VWT, 1024L * 2048, 2048, 2048,
      nullptr, 0L, 1024, nullptr, nullptr, out, 2048L * 1024, bout, 1.0f);
}

// Round 8
// 209.068 us; speedup vs baseline: 1.4183x; 1.4183x over previous
//
#include <hip/hip_runtime.h>
#include <cstdint>
#include <cstddef>

// ---------------------------------------------------------------------------
// SelfAttnV2: x[4,2048,1024] fp32 -> QKV proj -> softmax(QK^T/32) V -> out proj
// bf16 MFMA GEMMs, fp32 accum. Reassociated: (P.V).Wo == P.(V.Wo).
//  - QKV / VWT / PVW: gemm97 = 128x128, BK=32, 4 waves, 3-slot LDS ring
//    (48 KiB -> 3 blocks/CU), counted vmcnt gate, ONE barrier per K-iter.
//    R8: no manual lgkmcnt(0) drain before MFMA -- compiler emits fine-grained
//    waits so first MFMA starts when its first fragment lands.
//  - SC: 256x256 8-phase template, 256 blocks = 1 clean round; same fine-wait.
// ---------------------------------------------------------------------------

typedef __bf16 bf16;
typedef __bf16 bf16x8 __attribute__((ext_vector_type(8)));
typedef __bf16 bf16x4 __attribute__((ext_vector_type(4)));
typedef float  f32x4  __attribute__((ext_vector_type(4)));

#define UNIT 8192   // SC staging unit: 128 rows x 64 k = 16 KiB
#define U97  4096   // gemm97 unit: 128 rows x 32 k = 8 KiB

__device__ __forceinline__ void gload_lds16(const bf16* g, bf16* l) {
  __builtin_amdgcn_global_load_lds(
      (const __attribute__((address_space(1))) unsigned int*)g,
      (__attribute__((address_space(3))) unsigned int*)l, 16, 0, 0);
}

#define GATE(N)  asm volatile("s_waitcnt vmcnt(" #N ")" ::: "memory")
#define SBAR()   __builtin_amdgcn_s_barrier()
#define SCHED0() __builtin_amdgcn_sched_barrier(0)

// ===========================================================================
// gemm97: 128x128, BK=32, 256 threads = 4 waves (2x2), wave tile 64x64.
// LDS ring of 3 K-slots, each slot = A[128][32] + B[128][32] (16 KiB).
// Swizzle for 64B rows: slot' = s ^ ((r>>1)&3).
// ===========================================================================
__device__ __forceinline__ void stage97(const bf16* g0, long ld, bf16* u, int tid) {
  const int wv = tid >> 6;
  #pragma unroll
  for (int j = 0; j < 2; ++j) {
    const int c = j * 256 + tid;            // 0..511 chunks of 16B
    const int r = c >> 2, s = c & 3;
    const int sg = s ^ ((r >> 1) & 3);
    const int cb = j * 256 + (wv << 6);     // wave-uniform chunk base
    gload_lds16(g0 + (long)r * ld + sg * 8, u + (size_t)cb * 8);
  }
}

__device__ __forceinline__ bf16x8 rd97(const bf16* u, int r, int s) {
  return *(const bf16x8*)(u + (size_t)r * 32 + (size_t)((s ^ ((r >> 1) & 3)) * 8));
}

// MODE 0: QKV (+bias -> Q|K|V row-major)  MODE 2: bf16 store  MODE 3: fp32 (+bias)
template <int MODE>
__device__ __forceinline__ void gemm97_body(
    const bf16* __restrict__ A, long sAz, int lda,
    const bf16* __restrict__ B, long sBz, int ldb, int K,
    bf16* __restrict__ p0, long sCz, int ldc,
    bf16* __restrict__ p1, bf16* __restrict__ p2,
    float* __restrict__ fout, long sFz,
    const float* __restrict__ bias, float scale) {
  __shared__ bf16 lds[3][2][U97];   // 48 KiB -> 3 blocks/CU
  const int tid = threadIdx.x;
  const int wv = tid >> 6, ln = tid & 63;
  const int wr = wv >> 1, wc = wv & 1;     // 2x2 waves, 64x64 each
  const int lr = ln & 15, lh = ln >> 4;
  const int m0 = blockIdx.x * 128, n0 = blockIdx.y * 128;
  const int z = blockIdx.z;
  const bf16* Ag = A + (long)z * sAz + (long)m0 * lda;
  const bf16* Bg = B + (long)z * sBz + (long)n0 * ldb;
  const int NT = K / 32;

  stage97(Ag,      lda, &lds[0][0][0], tid);
  stage97(Bg,      ldb, &lds[0][1][0], tid);
  stage97(Ag + 32, lda, &lds[1][0][0], tid);
  stage97(Bg + 32, ldb, &lds[1][1][0], tid);
  GATE(4);
  SBAR();
  SCHED0();

  f32x4 acc[4][4];
  #pragma unroll
  for (int i = 0; i < 4; ++i)
    #pragma unroll
    for (int j = 0; j < 4; ++j) acc[i][j] = f32x4{0.f, 0.f, 0.f, 0.f};

  int rs = 0, ns = 2;
  for (int t = 0; t < NT; ++t) {
    const bf16* Au = &lds[rs][0][0];
    const bf16* Bu = &lds[rs][1][0];
    const bool pf = (t + 2 < NT);
    bf16x8 aF[4], bF[4];
    #pragma unroll
    for (int i = 0; i < 4; ++i) aF[i] = rd97(Au, wr * 64 + i * 16 + lr, lh);
    #pragma unroll
    for (int j = 0; j < 4; ++j) bF[j] = rd97(Bu, wc * 64 + j * 16 + lr, lh);
    if (pf) {
      stage97(Ag + (long)(t + 2) * 32, lda, &lds[ns][0][0], tid);
      stage97(Bg + (long)(t + 2) * 32, ldb, &lds[ns][1][0], tid);
    }
    // no manual lgkmcnt drain: compiler emits fine-grained waits per fragment
    __builtin_amdgcn_s_setprio(1);
    #pragma unroll
    for (int i = 0; i < 4; ++i)
      #pragma unroll
      for (int j = 0; j < 4; ++j)
        acc[i][j] = __builtin_amdgcn_mfma_f32_16x16x32_bf16(aF[i], bF[j], acc[i][j], 0, 0, 0);
    __builtin_amdgcn_s_setprio(0);
    if (t + 1 < NT) {
      if (pf) { GATE(4); } else { GATE(0); }
      SBAR();           // staging of slot(t+1) now visible to all waves
      SCHED0();         // pin next-iter ds_reads below the barrier
    }
    rs = (rs == 2) ? 0 : rs + 1;
    ns = (ns == 2) ? 0 : ns + 1;
  }

  // epilogue: C/D layout col=lane&15, row=(lane>>4)*4+reg
  #pragma unroll
  for (int mf = 0; mf < 4; ++mf) {
    #pragma unroll
    for (int nf = 0; nf < 4; ++nf) {
      #pragma unroll
      for (int rg = 0; rg < 4; ++rg) {
        const int gm = m0 + wr * 64 + mf * 16 + lh * 4 + rg;
        const int gn = n0 + wc * 64 + nf * 16 + lr;
        float v = acc[mf][nf][rg];
        if constexpr (MODE == 0) {
          v += bias[gn];
          if (gn < 1024)       p0[(size_t)gm * 1024 + gn] = (bf16)v;          // Q
          else if (gn < 2048)  p1[(size_t)gm * 1024 + (gn - 1024)] = (bf16)v; // K
          else                 p2[(size_t)gm * 1024 + (gn - 2048)] = (bf16)v; // V
        } else if constexpr (MODE == 2) {
          p0[(size_t)z * sCz + (size_t)gm * ldc + gn] = (bf16)(v * scale);
        } else {
          fout[(size_t)z * sFz + (size_t)gm * ldc + gn] = v + bias[gn];
        }
      }
    }
  }
}

#define GEMM_ARGS const bf16* A, long sAz, int lda, const bf16* B, long sBz, int ldb, \
                  int K, bf16* p0, long sCz, int ldc, bf16* p1, bf16* p2,             \
                  float* fout, long sFz, const float* bias, float scale
__global__ __launch_bounds__(256, 3) void gemm_qkv(GEMM_ARGS) {
  gemm97_body<0>(A, sAz, lda, B, sBz, ldb, K, p0, sCz, ldc, p1, p2, fout, sFz, bias, scale);
}
__global__ __launch_bounds__(256, 3) void gemm_vwt(GEMM_ARGS) {
  gemm97_body<2>(A, sAz, lda, B, sBz, ldb, K, p0, sCz, ldc, p1, p2, fout, sFz, bias, scale);
}
__global__ __launch_bounds__(256, 3) void gemm_pvw(GEMM_ARGS) {
  gemm97_body<3>(A, sAz, lda, B, sBz, ldb, K, p0, sCz, ldc, p1, p2, fout, sFz, bias, scale);
}

// ===========================================================================
// SC: 256x256 8-phase. 512 threads, 8 waves 2M x 4N; same fine-wait change.
// ===========================================================================
#define THREADS8 512

__device__ __forceinline__ void stage_unit(const bf16* g0, long ld, bf16* ldsu, int tid) {
  const int wv = tid >> 6;
  #pragma unroll
  for (int j = 0; j < 2; ++j) {
    const int c = j * 512 + tid;
    const int r = c >> 3;
    const int sg = (c & 7) ^ (r & 7);
    const int cb = j * 512 + (wv << 6);
    gload_lds16(g0 + (long)r * ld + sg * 8, ldsu + (size_t)cb * 8);
  }
}

__device__ __forceinline__ bf16x8 rd_frag(const bf16* unitb, int r, int s) {
  return *(const bf16x8*)(unitb + (size_t)r * 64 + (size_t)((s ^ (r & 7)) * 8));
}

#define PHASE(DB, MH, NH, RA, RB, STAGE_CODE, GATE_CODE)                         \
  {                                                                              \
    if (RA) {                                                                    \
      _Pragma("unroll") for (int mf = 0; mf < 4; ++mf)                           \
        _Pragma("unroll") for (int ks = 0; ks < 2; ++ks)                         \
          aF[mf][ks] = rd_frag(&lds[DB][MH][0], wsm * 64 + mf * 16 + lr, ks * 4 + lh); \
    }                                                                            \
    if (RB) {                                                                    \
      _Pragma("unroll") for (int nf = 0; nf < 2; ++nf)                           \
        _Pragma("unroll") for (int ks = 0; ks < 2; ++ks)                         \
          bF[NH][nf][ks] = rd_frag(&lds[DB][2 + NH][0], wsn * 32 + nf * 16 + lr, ks * 4 + lh); \
    }                                                                            \
    STAGE_CODE;                                                                  \
    SBAR();                                                                      \
    __builtin_amdgcn_s_setprio(1);                                               \
    _Pragma("unroll") for (int mf = 0; mf < 4; ++mf)                             \
      _Pragma("unroll") for (int nf = 0; nf < 2; ++nf)                           \
        _Pragma("unroll") for (int ks = 0; ks < 2; ++ks)                         \
          acc[(MH)*4 + mf][(NH)*2 + nf] = __builtin_amdgcn_mfma_f32_16x16x32_bf16( \
              aF[mf][ks], bF[NH][nf][ks], acc[(MH)*4 + mf][(NH)*2 + nf], 0, 0, 0); \
    __builtin_amdgcn_s_setprio(0);                                               \
    GATE_CODE;                                                                   \
    SBAR();                                                                      \
    SCHED0();                                                                    \
  }

__global__ __launch_bounds__(THREADS8, 2) void gemm_sc(
    const bf16* __restrict__ A, long sAz, int lda,
    const bf16* __restrict__ B, long sBz, int ldb, int K,
    bf16* __restrict__ p0, long sCz, float scale) {
  __shared__ bf16 lds[2][4][UNIT];   // 128 KiB
  const int tid = threadIdx.x;
  const int wv = tid >> 6, ln = tid & 63;
  const int wsm = wv >> 2, wsn = wv & 3;
  const int lr = ln & 15, lh = ln >> 4;

  const int gx = gridDim.x, gy = gridDim.y;
  const int lin = blockIdx.x + gx * (blockIdx.y + gy * blockIdx.z);
  const int nwg = gx * gy * gridDim.z;
  const int swz = (lin & 7) * (nwg >> 3) + (lin >> 3);
  const int by = swz % gy;
  const int t2 = swz / gy;
  const int bx = t2 % gx;
  const int z  = t2 / gx;

  const int m0 = bx * 256, n0 = by * 256;
  const bf16* Ag = A + (long)z * sAz + (long)m0 * lda;
  const bf16* Bg = B + (long)z * sBz + (long)n0 * ldb;
  const int NITER = K / 128;

  stage_unit(Ag,             lda, &lds[0][0][0], tid);
  stage_unit(Bg,             ldb, &lds[0][2][0], tid);
  stage_unit(Ag + 128 * lda, lda, &lds[0][1][0], tid);
  stage_unit(Bg + 128 * ldb, ldb, &lds[0][3][0], tid);
  stage_unit(Ag + 64,        lda, &lds[1][0][0], tid);
  stage_unit(Bg + 64,        ldb, &lds[1][2][0], tid);
  GATE(8);
  SBAR();
  SCHED0();

  f32x4 acc[8][4];
  #pragma unroll
  for (int i = 0; i < 8; ++i)
    #pragma unroll
    for (int j = 0; j < 4; ++j) acc[i][j] = f32x4{0.f, 0.f, 0.f, 0.f};
  bf16x8 aF[4][2], bF[2][2][2];

  for (int it = 0; it < NITER; ++it) {
    const bool nl = (it + 1 < NITER);
    const long ktA = 2L * it + 1, ktB = 2L * it + 2, ktC = 2L * it + 3;
    PHASE(0, 0, 0, 1, 1,
      { stage_unit(Ag + 128 * lda + ktA * 64, lda, &lds[1][1][0], tid); },
      { GATE(6); });
    PHASE(0, 0, 1, 0, 1,
      { stage_unit(Bg + 128 * ldb + ktA * 64, ldb, &lds[1][3][0], tid); },
      { GATE(10); });
    PHASE(0, 1, 0, 1, 0,
      { if (nl) stage_unit(Ag + ktB * 64, lda, &lds[0][0][0], tid); },
      {});
    PHASE(0, 1, 1, 0, 0,
      { if (nl) stage_unit(Bg + ktB * 64, ldb, &lds[0][2][0], tid); },
      { if (nl) { GATE(8); } else { GATE(4); } });
    PHASE(1, 0, 0, 1, 1,
      { if (nl) stage_unit(Ag + 128 * lda + ktB * 64, lda, &lds[0][1][0], tid); },
      { if (nl) { GATE(6); } else { GATE(0); } });
    PHASE(1, 0, 1, 0, 1,
      { if (nl) stage_unit(Bg + 128 * ldb + ktB * 64, ldb, &lds[0][3][0], tid); },
      { GATE(10); });
    PHASE(1, 1, 0, 1, 0,
      { if (nl) stage_unit(Ag + ktC * 64, lda, &lds[1][0][0], tid); },
      {});
    PHASE(1, 1, 1, 0, 0,
      { if (nl) stage_unit(Bg + ktC * 64, ldb, &lds[1][2][0], tid); },
      { GATE(8); });
  }

  #pragma unroll
  for (int mi = 0; mi < 8; ++mi) {
    #pragma unroll
    for (int ni = 0; ni < 4; ++ni) {
      #pragma unroll
      for (int rg = 0; rg < 4; ++rg) {
        const int gm = m0 + (mi >> 2) * 128 + wsm * 64 + (mi & 3) * 16 + lh * 4 + rg;
        const int gn = n0 + (ni >> 1) * 128 + wsn * 32 + (ni & 1) * 16 + lr;
        p0[(size_t)z * sCz + (size_t)gm * 2048 + gn] = (bf16)(acc[mi][ni][rg] * scale);
      }
    }
  }
}

// ===========================================================================
__global__ __launch_bounds__(256) void k_f32_to_bf16(const float* __restrict__ in,
                                                     bf16* __restrict__ out, long n) {
  long i = ((long)blockIdx.x * blockDim.x + threadIdx.x) * 4;
  if (i + 3 < n) {
    float4 v = *(const float4*)(in + i);
    bf16x4 o;
    o[0] = (bf16)v.x; o[1] = (bf16)v.y; o[2] = (bf16)v.z; o[3] = (bf16)v.w;
    *(bf16x4*)(out + i) = o;
  }
}

__global__ __launch_bounds__(256) void k_transpose(const float* __restrict__ in,
                                                   bf16* __restrict__ out, int R, int C) {
  __shared__ float t[32][33];
  int c0 = blockIdx.x * 32, r0 = blockIdx.y * 32;
  int tx = threadIdx.x, ty = threadIdx.y;
  #pragma unroll
  for (int dy = 0; dy < 32; dy += 8)
    t[ty + dy][tx] = in[(size_t)(r0 + ty + dy) * C + c0 + tx];
  __syncthreads();
  #pragma unroll
  for (int dy = 0; dy < 32; dy += 8)
    out[(size_t)(c0 + ty + dy) * R + r0 + tx] = (bf16)t[tx][ty + dy];
}

__global__ __launch_bounds__(256) void k_softmax(bf16* __restrict__ S) {
  const int row = blockIdx.x;
  bf16* p = S + (size_t)row * 2048;
  const int tid = threadIdx.x;
  bf16x8 vin = *(const bf16x8*)(p + tid * 8);
  float x[8];
  float mx = -1e30f;
  #pragma unroll
  for (int i = 0; i < 8; ++i) { x[i] = (float)vin[i]; mx = fmaxf(mx, x[i]); }
  #pragma unroll
  for (int off = 32; off; off >>= 1) mx = fmaxf(mx, __shfl_down(mx, off));
  __shared__ float redm[4];
  if ((tid & 63) == 0) redm[tid >> 6] = mx;
  __syncthreads();
  mx = fmaxf(fmaxf(redm[0], redm[1]), fmaxf(redm[2], redm[3]));
  float s = 0.f;
  #pragma unroll
  for (int i = 0; i < 8; ++i) { x[i] = __expf(x[i] - mx); s += x[i]; }
  #pragma unroll
  for (int off = 32; off; off >>= 1) s += __shfl_down(s, off);
  __shared__ float reds[4];
  if ((tid & 63) == 0) reds[tid >> 6] = s;
  __syncthreads();
  s = reds[0] + reds[1] + reds[2] + reds[3];
  float inv = 1.0f / s;
  bf16x8 vo;
  #pragma unroll
  for (int i = 0; i < 8; ++i) vo[i] = (bf16)(x[i] * inv);
  *(bf16x8*)(p + tid * 8) = vo;
}

// ---------------------------------------------------------------------------
extern "C" void kernel_launch(void* const* d_in, const int* in_sizes, int n_in,
                              void* d_out, int out_size, void* d_ws, size_t ws_size,
                              hipStream_t stream) {
  const float* x    = (const float*)d_in[0];
  const float* Wqkv = (const float*)d_in[1];
  const float* bqkv = (const float*)d_in[2];
  const float* Wout = (const float*)d_in[3];
  const float* bout = (const float*)d_in[4];
  float* out = (float*)d_out;

  char* w = (char*)d_ws;
  const size_t MB = 1ull << 20;
  bf16* Xb  = (bf16*)(w);             // 16MB
  bf16* WqT = (bf16*)(w + 16 * MB);   //  6MB
  bf16* WoT = (bf16*)(w + 22 * MB);   //  2MB
  bf16* Qb  = (bf16*)(w + 24 * MB);   // 16MB
  bf16* Kb  = (bf16*)(w + 40 * MB);   // 16MB
  bf16* Vb  = (bf16*)(w + 56 * MB);   // 16MB
  bf16* Sb  = (bf16*)(w + 72 * MB);   // 32MB (S -> P in place)
  bf16* VWT = (bf16*)(w + 104 * MB);  // 16MB [4][1024][2048]  (total 120MB)

  k_f32_to_bf16<<<8192, 256, 0, stream>>>(x, Xb, 8388608L);
  dim3 tb(32, 8);
  k_transpose<<<dim3(96, 32), tb, 0, stream>>>(Wqkv, WqT, 1024, 3072);
  k_transpose<<<dim3(32, 32), tb, 0, stream>>>(Wout, WoT, 1024, 1024);

  // QKV: [8192,1024] x W^T[3072,1024] + bias -> Q,K,V   (1536 blocks)
  gemm_qkv<<<dim3(64, 24), 256, 0, stream>>>(
      Xb, 0L, 1024, WqT, 0L, 1024, 1024,
      Qb, 0L, 1024, Kb, Vb, nullptr, 0L, bqkv, 1.0f);

  // VWT[z][d][s] = sum_h WoT[d][h] * V[z][s][h]   (512 blocks; V row-major)
  gemm_vwt<<<dim3(8, 16, 4), 256, 0, stream>>>(
      WoT, 0L, 1024, Vb, 2048L * 1024, 1024, 1024,
      VWT, 1024L * 2048, 2048, nullptr, nullptr, nullptr, 0L, nullptr, 1.0f);

  // scores: per batch Q x K^T * 1/32   (8-phase 256^2, 256 blocks = 1 round)
  gemm_sc<<<dim3(8, 8, 4), THREADS8, 0, stream>>>(
      Qb, 2048L * 1024, 1024, Kb, 2048L * 1024, 1024, 1024,
      Sb, 2048L * 2048, 0.03125f);

  k_softmax<<<8192, 256, 0, stream>>>(Sb);

  // out[z][q][d] = sum_s P[z][q][s] * VWT[z][d][s] + bout[d]   (512 blocks, fp32)
  gemm_pvw<<<dim3(16, 8, 4), 256, 0, stream>>>(
      Sb, 2048L * 2048, 2048, VWT, 1024L * 2048, 2048, 2048,
      nullptr, 0L, 1024, nullptr, nullptr, out, 2048L * 1024, bout, 1.0f);
}